// Round 1
// baseline (214.241 us; speedup 1.0000x reference)
//
#include <hip/hip_runtime.h>
#include <hip/hip_bf16.h>

#define BB 2
#define SS 2048
#define EE 768
#define HH 12
#define DD 64
#define MM (BB*SS)   // 4096 token rows

typedef __bf16 bf16_t;
typedef __bf16 bf16x8 __attribute__((ext_vector_type(8)));
typedef __bf16 bf16x4 __attribute__((ext_vector_type(4)));
typedef float  f32x4  __attribute__((ext_vector_type(4)));

static __device__ __forceinline__ f32x4 mfma16(bf16x8 a, bf16x8 b, f32x4 c) {
    return __builtin_amdgcn_mfma_f32_16x16x32_bf16(a, b, c, 0, 0, 0);
}

// ---------------- cast x (f32 -> bf16) ----------------
__global__ void cast_x_kernel(const float* __restrict__ x, bf16_t* __restrict__ xb, int n) {
    int i = (blockIdx.x * 256 + threadIdx.x) * 8;
    if (i >= n) return;
    float4 a = *reinterpret_cast<const float4*>(x + i);
    float4 b = *reinterpret_cast<const float4*>(x + i + 4);
    bf16x8 v;
    v[0] = (bf16_t)a.x; v[1] = (bf16_t)a.y; v[2] = (bf16_t)a.z; v[3] = (bf16_t)a.w;
    v[4] = (bf16_t)b.x; v[5] = (bf16_t)b.y; v[6] = (bf16_t)b.z; v[7] = (bf16_t)b.w;
    *reinterpret_cast<bf16x8*>(xb + i) = v;
}

// ---------------- W [K][N] f32 -> WT [N][K] bf16 ----------------
__global__ void transpose_cast_kernel(const float* __restrict__ W, bf16_t* __restrict__ WT,
                                      int K, int N) {
    __shared__ float tile[32][33];
    int n0 = blockIdx.x * 32, k0 = blockIdx.y * 32;
    int tx = threadIdx.x & 31, ty = threadIdx.x >> 5;   // 256 thr = 32x8
    #pragma unroll
    for (int r = 0; r < 32; r += 8)
        tile[ty + r][tx] = W[(size_t)(k0 + ty + r) * N + n0 + tx];
    __syncthreads();
    #pragma unroll
    for (int r = 0; r < 32; r += 8)
        WT[(size_t)(n0 + ty + r) * K + k0 + tx] = (bf16_t)tile[tx][ty + r];
}

// ---------------- RoPE tables: cos/sin [2048][32] ----------------
__global__ void rope_table_kernel(float* __restrict__ ctab, float* __restrict__ stab) {
    int t = blockIdx.x * 256 + threadIdx.x;     // 65536
    int s = t >> 5, j = t & 31;
    float theta = exp2f(-(float)j * (13.287712379549449f / 32.0f)); // 10000^(-j/32)
    float ang = (float)s * theta;
    float sn, cs;
    sincosf(ang, &sn, &cs);
    ctab[t] = cs;
    stab[t] = sn;
}

// ---------------- fused QKV projection + bias/scale + RoPE ----------------
// Q,K -> Qr/Kr [b][branch][h][s][d] bf16 ; V -> Vt [b][h][d][s] bf16
__global__ __launch_bounds__(256)
void gemm_qkv_kernel(const bf16_t* __restrict__ xb,
                     const bf16_t* __restrict__ WqT, const bf16_t* __restrict__ WkT,
                     const bf16_t* __restrict__ WvT,
                     const float* __restrict__ bq, const float* __restrict__ bk,
                     const float* __restrict__ bv,
                     const float* __restrict__ qs, const float* __restrict__ ks,
                     const float* __restrict__ vs,
                     const float* __restrict__ ctab, const float* __restrict__ stab,
                     bf16_t* __restrict__ Qr, bf16_t* __restrict__ Kr, bf16_t* __restrict__ Vt)
{
    __shared__ __align__(16) bf16_t As[128][72];
    __shared__ __align__(16) bf16_t Bs[128][72];
    const int tid = threadIdx.x;
    const int w = tid >> 6, lane = tid & 63, q15 = lane & 15, g = lane >> 4;
    const int m0 = blockIdx.x * 128;
    const int nt = blockIdx.y;

    const bf16_t* Wsrc; const float* bias; const float* scale;
    int nloc0, mode; bf16_t* dstQK = nullptr;
    if (nt < 12)      { Wsrc = WqT; bias = bq; scale = qs; nloc0 = nt * 128;        mode = 0; dstQK = Qr; }
    else if (nt < 24) { Wsrc = WkT; bias = bk; scale = ks; nloc0 = (nt - 12) * 128; mode = 0; dstQK = Kr; }
    else              { Wsrc = WvT; bias = bv; scale = vs; nloc0 = (nt - 24) * 128; mode = 1; }

    f32x4 acc[4][4];
    #pragma unroll
    for (int i = 0; i < 4; ++i)
        #pragma unroll
        for (int j = 0; j < 4; ++j)
            acc[i][j] = f32x4{0.f, 0.f, 0.f, 0.f};

    const int srow = tid >> 3, scol = (tid & 7) * 8;
    for (int k0 = 0; k0 < 768; k0 += 64) {
        #pragma unroll
        for (int rr = srow; rr < 128; rr += 32) {
            *reinterpret_cast<bf16x8*>(&As[rr][scol]) =
                *reinterpret_cast<const bf16x8*>(&xb[(size_t)(m0 + rr) * 768 + k0 + scol]);
            *reinterpret_cast<bf16x8*>(&Bs[rr][scol]) =
                *reinterpret_cast<const bf16x8*>(&Wsrc[(size_t)(nloc0 + rr) * 768 + k0 + scol]);
        }
        __syncthreads();
        const int ar0 = (w >> 1) * 64, bc0 = (w & 1) * 64;
        #pragma unroll
        for (int st = 0; st < 2; ++st) {
            bf16x8 af[4], bfr[4];
            #pragma unroll
            for (int i = 0; i < 4; ++i)
                af[i] = *reinterpret_cast<const bf16x8*>(&As[ar0 + i * 16 + q15][st * 32 + g * 8]);
            #pragma unroll
            for (int j = 0; j < 4; ++j)
                bfr[j] = *reinterpret_cast<const bf16x8*>(&Bs[bc0 + j * 16 + q15][st * 32 + g * 8]);
            #pragma unroll
            for (int i = 0; i < 4; ++i)
                #pragma unroll
                for (int j = 0; j < 4; ++j)
                    acc[i][j] = mfma16(af[i], bfr[j], acc[i][j]);
        }
        __syncthreads();
    }

    const int mbase = m0 + (w >> 1) * 64;
    const int nbase = nloc0 + (w & 1) * 64;
    #pragma unroll
    for (int j = 0; j < 4; ++j) {
        const int n = nbase + j * 16 + q15;
        const float bi = bias[n], sc = scale[n];
        if (mode == 1) {
            const int h = n >> 6, d = n & 63;
            #pragma unroll
            for (int i = 0; i < 4; ++i)
                #pragma unroll
                for (int r = 0; r < 4; ++r) {
                    int m = mbase + i * 16 + g * 4 + r;
                    int b = m >> 11, s = m & 2047;
                    float v = (acc[i][j][r] + bi) * sc;
                    Vt[((size_t)(b * HH + h) * DD + d) * SS + s] = (bf16_t)v;
                }
        } else {
            const int br = (n >= 768) ? 1 : 0;
            const int n2 = n - br * 768;
            const int h = n2 >> 6, d = n2 & 63, jj = d >> 1;
            #pragma unroll
            for (int i = 0; i < 4; ++i)
                #pragma unroll
                for (int r = 0; r < 4; ++r) {
                    int m = mbase + i * 16 + g * 4 + r;
                    int b = m >> 11, s = m & 2047;
                    float v = (acc[i][j][r] + bi) * sc;
                    float p = __shfl_xor(v, 1);            // partner column d^1, same row
                    float cs = ctab[s * 32 + jj], sn = stab[s * 32 + jj];
                    float outv = (d & 1) ? (p * sn + v * cs) : (v * cs - p * sn);
                    dstQK[(((size_t)(b * 2 + br) * HH + h) * SS + s) * DD + d] = (bf16_t)outv;
                }
        }
    }
}

// ---------------- attention branch step (swapped QK^T, P in registers) ----------------
static __device__ __forceinline__ void attn_branch(
    const bf16_t (* __restrict__ Ks)[72], const bf16x8 qf[2],
    const bf16_t (* __restrict__ Vs)[72],
    int q15, int g, float& m, float& l, f32x4 O[4])
{
    // S^T tile: D[key][q] ; lane holds keys rf*16 + g*4 + r for q = q15
    f32x4 sf[4];
    #pragma unroll
    for (int rf = 0; rf < 4; ++rf) {
        f32x4 a = f32x4{0.f, 0.f, 0.f, 0.f};
        #pragma unroll
        for (int st = 0; st < 2; ++st) {
            bf16x8 kf = *reinterpret_cast<const bf16x8*>(&Ks[rf * 16 + q15][st * 32 + g * 8]);
            a = mfma16(kf, qf[st], a);
        }
        sf[rf] = a;
    }
    float cmax = -3.0e38f;
    #pragma unroll
    for (int rf = 0; rf < 4; ++rf)
        #pragma unroll
        for (int r = 0; r < 4; ++r) {
            float v = sf[rf][r] * 0.125f;   // 1/sqrt(64)
            sf[rf][r] = v;
            cmax = fmaxf(cmax, v);
        }
    cmax = fmaxf(cmax, __shfl_xor(cmax, 16));
    cmax = fmaxf(cmax, __shfl_xor(cmax, 32));
    float mnew = fmaxf(m, cmax);
    float fsc = __expf(m - mnew);
    float psum = 0.f;
    bf16x8 pa[2];   // A-operand slots: key = st*32 + (e<4 ? g*4+e : 16+g*4+e-4)
    #pragma unroll
    for (int st = 0; st < 2; ++st)
        #pragma unroll
        for (int e = 0; e < 8; ++e) {
            float p = __expf(sf[st * 2 + (e >> 2)][e & 3] - mnew);
            psum += p;
            pa[st][e] = (bf16_t)p;
        }
    psum += __shfl_xor(psum, 16);
    psum += __shfl_xor(psum, 32);
    l = l * fsc + psum;
    m = mnew;
    float fr[4];
    #pragma unroll
    for (int r = 0; r < 4; ++r) fr[r] = __shfl(fsc, g * 4 + r);
    #pragma unroll
    for (int df = 0; df < 4; ++df) {
        O[df][0] *= fr[0]; O[df][1] *= fr[1]; O[df][2] *= fr[2]; O[df][3] *= fr[3];
    }
    // PV: B-operand reads V with the SAME key-slot mapping as pa (permutation cancels)
    #pragma unroll
    for (int st = 0; st < 2; ++st)
        #pragma unroll
        for (int df = 0; df < 4; ++df) {
            bf16x4 lo = *reinterpret_cast<const bf16x4*>(&Vs[df * 16 + q15][st * 32 + g * 4]);
            bf16x4 hi = *reinterpret_cast<const bf16x4*>(&Vs[df * 16 + q15][st * 32 + 16 + g * 4]);
            bf16x8 vf;
            vf[0] = lo[0]; vf[1] = lo[1]; vf[2] = lo[2]; vf[3] = lo[3];
            vf[4] = hi[0]; vf[5] = hi[1]; vf[6] = hi[2]; vf[7] = hi[3];
            O[df] = mfma16(pa[st], vf, O[df]);
        }
}

// ---------------- differential attention + per-head LN ----------------
__global__ __launch_bounds__(256)
void attn_kernel(const bf16_t* __restrict__ Qr, const bf16_t* __restrict__ Kr,
                 const bf16_t* __restrict__ Vt, const float* __restrict__ lambda_param,
                 bf16_t* __restrict__ ctx)
{
    __shared__ __align__(16) bf16_t K1s[64][72];
    __shared__ __align__(16) bf16_t K2s[64][72];
    __shared__ __align__(16) bf16_t Vs[64][72];   // [d][key]

    const int bh = blockIdx.y, b = bh / HH, h = bh % HH;
    const int s0 = blockIdx.x * 64;
    const int tid = threadIdx.x, w = tid >> 6, lane = tid & 63, q15 = lane & 15, g = lane >> 4;
    const float lam = 1.0f / (1.0f + __expf(-lambda_param[0]));

    const bf16_t* Q1p = Qr + (((size_t)(b * 2 + 0) * HH + h) * SS + (s0 + w * 16 + q15)) * DD;
    const bf16_t* Q2p = Qr + (((size_t)(b * 2 + 1) * HH + h) * SS + (s0 + w * 16 + q15)) * DD;
    bf16x8 qf1[2], qf2[2];
    qf1[0] = *reinterpret_cast<const bf16x8*>(Q1p + g * 8);
    qf1[1] = *reinterpret_cast<const bf16x8*>(Q1p + 32 + g * 8);
    qf2[0] = *reinterpret_cast<const bf16x8*>(Q2p + g * 8);
    qf2[1] = *reinterpret_cast<const bf16x8*>(Q2p + 32 + g * 8);

    const bf16_t* K1base = Kr + ((size_t)(b * 2 + 0) * HH + h) * SS * DD;
    const bf16_t* K2base = Kr + ((size_t)(b * 2 + 1) * HH + h) * SS * DD;
    const bf16_t* Vbase  = Vt + ((size_t)b * HH + h) * DD * SS;   // row d, stride SS

    float m1 = -3.0e38f, l1 = 0.f, m2 = -3.0e38f, l2 = 0.f;
    f32x4 O1[4], O2[4];
    #pragma unroll
    for (int df = 0; df < 4; ++df) {
        O1[df] = f32x4{0.f, 0.f, 0.f, 0.f};
        O2[df] = f32x4{0.f, 0.f, 0.f, 0.f};
    }

    const int srow = tid >> 3, scol = (tid & 7) * 8;
    for (int kb = 0; kb < SS; kb += 64) {
        #pragma unroll
        for (int r2 = srow; r2 < 64; r2 += 32) {
            *reinterpret_cast<bf16x8*>(&K1s[r2][scol]) =
                *reinterpret_cast<const bf16x8*>(&K1base[(size_t)(kb + r2) * DD + scol]);
            *reinterpret_cast<bf16x8*>(&K2s[r2][scol]) =
                *reinterpret_cast<const bf16x8*>(&K2base[(size_t)(kb + r2) * DD + scol]);
            *reinterpret_cast<bf16x8*>(&Vs[r2][scol]) =
                *reinterpret_cast<const bf16x8*>(&Vbase[(size_t)r2 * SS + kb + scol]);
        }
        __syncthreads();
        attn_branch(K1s, qf1, Vs, q15, g, m1, l1, O1);
        attn_branch(K2s, qf2, Vs, q15, g, m2, l2, O2);
        __syncthreads();
    }

    float rl1[4], rl2[4];
    #pragma unroll
    for (int r = 0; r < 4; ++r) {
        rl1[r] = __shfl(l1, g * 4 + r);
        rl2[r] = __shfl(l2, g * 4 + r);
    }
    float cv[4][4];   // [df][r]
    #pragma unroll
    for (int df = 0; df < 4; ++df)
        #pragma unroll
        for (int r = 0; r < 4; ++r)
            cv[df][r] = O1[df][r] / rl1[r] - lam * (O2[df][r] / rl2[r]);

    #pragma unroll
    for (int r = 0; r < 4; ++r) {
        float sum = cv[0][r] + cv[1][r] + cv[2][r] + cv[3][r];
        sum += __shfl_xor(sum, 1); sum += __shfl_xor(sum, 2);
        sum += __shfl_xor(sum, 4); sum += __shfl_xor(sum, 8);
        float mu = sum * (1.0f / 64.0f);
        float vac = 0.f;
        #pragma unroll
        for (int df = 0; df < 4; ++df) { float dv = cv[df][r] - mu; vac += dv * dv; }
        vac += __shfl_xor(vac, 1); vac += __shfl_xor(vac, 2);
        vac += __shfl_xor(vac, 4); vac += __shfl_xor(vac, 8);
        float rs = rsqrtf(vac * (1.0f / 64.0f) + 1e-5f);
        int s = s0 + w * 16 + g * 4 + r;
        size_t rowoff = ((size_t)b * SS + s) * EE + h * DD;
        #pragma unroll
        for (int df = 0; df < 4; ++df)
            ctx[rowoff + df * 16 + q15] = (bf16_t)((cv[df][r] - mu) * rs * 0.5f);
    }
}

// ---------------- output projection: out = (ctx @ Wo + bo) * o_scale (f32) ----------------
__global__ __launch_bounds__(256)
void gemm_out_kernel(const bf16_t* __restrict__ ctxb, const bf16_t* __restrict__ WoT,
                     const float* __restrict__ bo, const float* __restrict__ os,
                     float* __restrict__ out)
{
    __shared__ __align__(16) bf16_t As[128][72];
    __shared__ __align__(16) bf16_t Bs[128][72];
    const int tid = threadIdx.x;
    const int w = tid >> 6, lane = tid & 63, q15 = lane & 15, g = lane >> 4;
    const int m0 = blockIdx.x * 128;
    const int nloc0 = blockIdx.y * 128;

    f32x4 acc[4][4];
    #pragma unroll
    for (int i = 0; i < 4; ++i)
        #pragma unroll
        for (int j = 0; j < 4; ++j)
            acc[i][j] = f32x4{0.f, 0.f, 0.f, 0.f};

    const int srow = tid >> 3, scol = (tid & 7) * 8;
    for (int k0 = 0; k0 < 768; k0 += 64) {
        #pragma unroll
        for (int rr = srow; rr < 128; rr += 32) {
            *reinterpret_cast<bf16x8*>(&As[rr][scol]) =
                *reinterpret_cast<const bf16x8*>(&ctxb[(size_t)(m0 + rr) * 768 + k0 + scol]);
            *reinterpret_cast<bf16x8*>(&Bs[rr][scol]) =
                *reinterpret_cast<const bf16x8*>(&WoT[(size_t)(nloc0 + rr) * 768 + k0 + scol]);
        }
        __syncthreads();
        const int ar0 = (w >> 1) * 64, bc0 = (w & 1) * 64;
        #pragma unroll
        for (int st = 0; st < 2; ++st) {
            bf16x8 af[4], bfr[4];
            #pragma unroll
            for (int i = 0; i < 4; ++i)
                af[i] = *reinterpret_cast<const bf16x8*>(&As[ar0 + i * 16 + q15][st * 32 + g * 8]);
            #pragma unroll
            for (int j = 0; j < 4; ++j)
                bfr[j] = *reinterpret_cast<const bf16x8*>(&Bs[bc0 + j * 16 + q15][st * 32 + g * 8]);
            #pragma unroll
            for (int i = 0; i < 4; ++i)
                #pragma unroll
                for (int j = 0; j < 4; ++j)
                    acc[i][j] = mfma16(af[i], bfr[j], acc[i][j]);
        }
        __syncthreads();
    }

    const int mbase = m0 + (w >> 1) * 64;
    const int nbase = nloc0 + (w & 1) * 64;
    #pragma unroll
    for (int j = 0; j < 4; ++j) {
        const int n = nbase + j * 16 + q15;
        const float bi = bo[n], sc = os[n];
        #pragma unroll
        for (int i = 0; i < 4; ++i)
            #pragma unroll
            for (int r = 0; r < 4; ++r) {
                int m = mbase + i * 16 + g * 4 + r;
                out[(size_t)m * 768 + n] = (acc[i][j][r] + bi) * sc;
            }
    }
}

// ---------------- launch ----------------
extern "C" void kernel_launch(void* const* d_in, const int* in_sizes, int n_in,
                              void* d_out, int out_size, void* d_ws, size_t ws_size,
                              hipStream_t stream)
{
    (void)in_sizes; (void)n_in; (void)out_size; (void)ws_size;
    const float* x  = (const float*)d_in[0];
    const float* Wq = (const float*)d_in[1];
    const float* bq = (const float*)d_in[2];
    const float* Wk = (const float*)d_in[3];
    const float* bk = (const float*)d_in[4];
    const float* Wv = (const float*)d_in[5];
    const float* bv = (const float*)d_in[6];
    const float* Wo = (const float*)d_in[7];
    const float* bo = (const float*)d_in[8];
    const float* qs = (const float*)d_in[9];
    const float* ks = (const float*)d_in[10];
    const float* vs = (const float*)d_in[11];
    const float* os = (const float*)d_in[12];
    const float* lp = (const float*)d_in[13];
    float* out = (float*)d_out;

    char* ws = (char*)d_ws;
    bf16_t* xb   = (bf16_t*)(ws);                  // 4096*768*2      = 6291456
    bf16_t* WqT  = (bf16_t*)(ws + 6291456);        // 1536*768*2      = 2359296
    bf16_t* WkT  = (bf16_t*)(ws + 8650752);        // 2359296
    bf16_t* WvT  = (bf16_t*)(ws + 11010048);       // 768*768*2       = 1179648
    bf16_t* WoT  = (bf16_t*)(ws + 12189696);       // 1179648
    bf16_t* Qr   = (bf16_t*)(ws + 13369344);       // 2*2*12*2048*64*2 = 12582912
    bf16_t* Kr   = (bf16_t*)(ws + 25952256);       // 12582912
    bf16_t* Vt   = (bf16_t*)(ws + 38535168);       // 2*12*64*2048*2  = 6291456
    bf16_t* ctxb = (bf16_t*)(ws + 44826624);       // 4096*768*2      = 6291456
    float*  ctab = (float*)(ws + 51118080);        // 2048*32*4       = 262144
    float*  stab = (float*)(ws + 51380224);        // 262144  -> total 51642368

    cast_x_kernel<<<dim3(1536), dim3(256), 0, stream>>>(x, xb, MM * EE);
    transpose_cast_kernel<<<dim3(48, 24), dim3(256), 0, stream>>>(Wq, WqT, 768, 1536);
    transpose_cast_kernel<<<dim3(48, 24), dim3(256), 0, stream>>>(Wk, WkT, 768, 1536);
    transpose_cast_kernel<<<dim3(24, 24), dim3(256), 0, stream>>>(Wv, WvT, 768, 768);
    transpose_cast_kernel<<<dim3(24, 24), dim3(256), 0, stream>>>(Wo, WoT, 768, 768);
    rope_table_kernel<<<dim3(256), dim3(256), 0, stream>>>(ctab, stab);
    gemm_qkv_kernel<<<dim3(32, 30), dim3(256), 0, stream>>>(xb, WqT, WkT, WvT,
                                                            bq, bk, bv, qs, ks, vs,
                                                            ctab, stab, Qr, Kr, Vt);
    attn_kernel<<<dim3(32, 24), dim3(256), 0, stream>>>(Qr, Kr, Vt, lp, ctxb);
    gemm_out_kernel<<<dim3(32, 6), dim3(256), 0, stream>>>(ctxb, WoT, bo, os, out);
}

// Round 2
// 208.414 us; speedup vs baseline: 1.0280x; 1.0280x over previous
//
#include <hip/hip_runtime.h>
#include <hip/hip_bf16.h>

#define BB 2
#define SS 2048
#define EE 768
#define HH 12
#define DD 64
#define MM (BB*SS)   // 4096 token rows

typedef __bf16 bf16_t;
typedef __bf16 bf16x8 __attribute__((ext_vector_type(8)));
typedef __bf16 bf16x4 __attribute__((ext_vector_type(4)));
typedef float  f32x4  __attribute__((ext_vector_type(4)));

static __device__ __forceinline__ f32x4 mfma16(bf16x8 a, bf16x8 b, f32x4 c) {
    return __builtin_amdgcn_mfma_f32_16x16x32_bf16(a, b, c, 0, 0, 0);
}

// ---------------- cast x (f32 -> bf16) ----------------
__global__ void cast_x_kernel(const float* __restrict__ x, bf16_t* __restrict__ xb, int n) {
    int i = (blockIdx.x * 256 + threadIdx.x) * 8;
    if (i >= n) return;
    float4 a = *reinterpret_cast<const float4*>(x + i);
    float4 b = *reinterpret_cast<const float4*>(x + i + 4);
    bf16x8 v;
    v[0] = (bf16_t)a.x; v[1] = (bf16_t)a.y; v[2] = (bf16_t)a.z; v[3] = (bf16_t)a.w;
    v[4] = (bf16_t)b.x; v[5] = (bf16_t)b.y; v[6] = (bf16_t)b.z; v[7] = (bf16_t)b.w;
    *reinterpret_cast<bf16x8*>(xb + i) = v;
}

// ---------------- W [K][N] f32 -> WT [N][K] bf16 ----------------
__global__ void transpose_cast_kernel(const float* __restrict__ W, bf16_t* __restrict__ WT,
                                      int K, int N) {
    __shared__ float tile[32][33];
    int n0 = blockIdx.x * 32, k0 = blockIdx.y * 32;
    int tx = threadIdx.x & 31, ty = threadIdx.x >> 5;   // 256 thr = 32x8
    #pragma unroll
    for (int r = 0; r < 32; r += 8)
        tile[ty + r][tx] = W[(size_t)(k0 + ty + r) * N + n0 + tx];
    __syncthreads();
    #pragma unroll
    for (int r = 0; r < 32; r += 8)
        WT[(size_t)(n0 + ty + r) * K + k0 + tx] = (bf16_t)tile[tx][ty + r];
}

// ---------------- RoPE tables: cos/sin [2048][32] ----------------
__global__ void rope_table_kernel(float* __restrict__ ctab, float* __restrict__ stab) {
    int t = blockIdx.x * 256 + threadIdx.x;     // 65536
    int s = t >> 5, j = t & 31;
    float theta = exp2f(-(float)j * (13.287712379549449f / 32.0f)); // 10000^(-j/32)
    float ang = (float)s * theta;
    float sn, cs;
    sincosf(ang, &sn, &cs);
    ctab[t] = cs;
    stab[t] = sn;
}

// ---------------- fused QKV projection + bias/scale + RoPE ----------------
// Q,K -> Qr/Kr [b][branch][h][s][d] bf16 (Q pre-scaled by 1/8) ; V -> Vt [b][h][d][s] bf16
__global__ __launch_bounds__(256)
void gemm_qkv_kernel(const bf16_t* __restrict__ xb,
                     const bf16_t* __restrict__ WqT, const bf16_t* __restrict__ WkT,
                     const bf16_t* __restrict__ WvT,
                     const float* __restrict__ bq, const float* __restrict__ bk,
                     const float* __restrict__ bv,
                     const float* __restrict__ qs, const float* __restrict__ ks,
                     const float* __restrict__ vs,
                     const float* __restrict__ ctab, const float* __restrict__ stab,
                     bf16_t* __restrict__ Qr, bf16_t* __restrict__ Kr, bf16_t* __restrict__ Vt)
{
    __shared__ __align__(16) bf16_t As[128][72];
    __shared__ __align__(16) bf16_t Bs[128][72];
    const int tid = threadIdx.x;
    const int w = tid >> 6, lane = tid & 63, q15 = lane & 15, g = lane >> 4;
    const int m0 = blockIdx.x * 128;
    const int nt = blockIdx.y;

    const bf16_t* Wsrc; const float* bias; const float* scale;
    int nloc0, mode; bf16_t* dstQK = nullptr; float qmul = 1.0f;
    if (nt < 12)      { Wsrc = WqT; bias = bq; scale = qs; nloc0 = nt * 128;        mode = 0; dstQK = Qr; qmul = 0.125f; }
    else if (nt < 24) { Wsrc = WkT; bias = bk; scale = ks; nloc0 = (nt - 12) * 128; mode = 0; dstQK = Kr; }
    else              { Wsrc = WvT; bias = bv; scale = vs; nloc0 = (nt - 24) * 128; mode = 1; }

    f32x4 acc[4][4];
    #pragma unroll
    for (int i = 0; i < 4; ++i)
        #pragma unroll
        for (int j = 0; j < 4; ++j)
            acc[i][j] = f32x4{0.f, 0.f, 0.f, 0.f};

    const int srow = tid >> 3, scol = (tid & 7) * 8;
    for (int k0 = 0; k0 < 768; k0 += 64) {
        #pragma unroll
        for (int rr = srow; rr < 128; rr += 32) {
            *reinterpret_cast<bf16x8*>(&As[rr][scol]) =
                *reinterpret_cast<const bf16x8*>(&xb[(size_t)(m0 + rr) * 768 + k0 + scol]);
            *reinterpret_cast<bf16x8*>(&Bs[rr][scol]) =
                *reinterpret_cast<const bf16x8*>(&Wsrc[(size_t)(nloc0 + rr) * 768 + k0 + scol]);
        }
        __syncthreads();
        const int ar0 = (w >> 1) * 64, bc0 = (w & 1) * 64;
        #pragma unroll
        for (int st = 0; st < 2; ++st) {
            bf16x8 af[4], bfr[4];
            #pragma unroll
            for (int i = 0; i < 4; ++i)
                af[i] = *reinterpret_cast<const bf16x8*>(&As[ar0 + i * 16 + q15][st * 32 + g * 8]);
            #pragma unroll
            for (int j = 0; j < 4; ++j)
                bfr[j] = *reinterpret_cast<const bf16x8*>(&Bs[bc0 + j * 16 + q15][st * 32 + g * 8]);
            #pragma unroll
            for (int i = 0; i < 4; ++i)
                #pragma unroll
                for (int j = 0; j < 4; ++j)
                    acc[i][j] = mfma16(af[i], bfr[j], acc[i][j]);
        }
        __syncthreads();
    }

    const int mbase = m0 + (w >> 1) * 64;
    const int nbase = nloc0 + (w & 1) * 64;
    #pragma unroll
    for (int j = 0; j < 4; ++j) {
        const int n = nbase + j * 16 + q15;
        const float bi = bias[n];
        const float sc = scale[n] * qmul;
        if (mode == 1) {
            const int h = n >> 6, d = n & 63;
            #pragma unroll
            for (int i = 0; i < 4; ++i)
                #pragma unroll
                for (int r = 0; r < 4; ++r) {
                    int m = mbase + i * 16 + g * 4 + r;
                    int b = m >> 11, s = m & 2047;
                    float v = (acc[i][j][r] + bi) * sc;
                    Vt[((size_t)(b * HH + h) * DD + d) * SS + s] = (bf16_t)v;
                }
        } else {
            const int br = (n >= 768) ? 1 : 0;
            const int n2 = n - br * 768;
            const int h = n2 >> 6, d = n2 & 63, jj = d >> 1;
            #pragma unroll
            for (int i = 0; i < 4; ++i)
                #pragma unroll
                for (int r = 0; r < 4; ++r) {
                    int m = mbase + i * 16 + g * 4 + r;
                    int b = m >> 11, s = m & 2047;
                    float v = (acc[i][j][r] + bi) * sc;   // scale folded BEFORE rope (linear)
                    float p = __shfl_xor(v, 1);            // partner column d^1, same row
                    float cs = ctab[s * 32 + jj], sn = stab[s * 32 + jj];
                    float outv = (d & 1) ? (p * sn + v * cs) : (v * cs - p * sn);
                    dstQK[(((size_t)(b * 2 + br) * HH + h) * SS + s) * DD + d] = (bf16_t)outv;
                }
        }
    }
}

// ---------------- attention branch step (swapped QK^T, P in registers, defer-max) ----------
// Ks: [key][72] row-major K tile. Vs: [d][72] with keys PRE-PERMUTED into B-fragment
// k-slot order: slot u = st*32 + g*8 + e holds key st*32 + (e>>2)*16 + g*4 + (e&3).
static __device__ __forceinline__ void attn_branch(
    const bf16_t (* __restrict__ Ks)[72], const bf16x8 qf[2],
    const bf16_t (* __restrict__ Vs)[72],
    int q15, int g, float& m, float& lsum, f32x4 O[4])
{
    // S^T tile: lane holds scores for q = q15, keys rf*16 + g*4 + r
    f32x4 sf[4];
    #pragma unroll
    for (int rf = 0; rf < 4; ++rf) {
        f32x4 a = f32x4{0.f, 0.f, 0.f, 0.f};
        #pragma unroll
        for (int st = 0; st < 2; ++st) {
            bf16x8 kf = *reinterpret_cast<const bf16x8*>(&Ks[rf * 16 + q15][st * 32 + g * 8]);
            a = mfma16(kf, qf[st], a);
        }
        sf[rf] = a;
    }
    float cmax = -3.0e38f;
    #pragma unroll
    for (int rf = 0; rf < 4; ++rf)
        #pragma unroll
        for (int r = 0; r < 4; ++r)
            cmax = fmaxf(cmax, sf[rf][r]);
    cmax = fmaxf(cmax, __shfl_xor(cmax, 16));
    cmax = fmaxf(cmax, __shfl_xor(cmax, 32));   // row max for q = q15

    if (__any(cmax - m > 8.0f)) {               // rare: rescale path (wave-uniform)
        float mnew = fmaxf(m, cmax);
        float fsc = __expf(m - mnew);
        lsum *= fsc;
        m = mnew;
        float fr[4];
        #pragma unroll
        for (int r = 0; r < 4; ++r) fr[r] = __shfl(fsc, g * 4 + r);
        #pragma unroll
        for (int df = 0; df < 4; ++df) {
            O[df][0] *= fr[0]; O[df][1] *= fr[1]; O[df][2] *= fr[2]; O[df][3] *= fr[3];
        }
    }

    bf16x8 pa[2];   // A-operand: slot (st,e) = key st*32 + (e>>2)*16 + g*4 + (e&3)
    #pragma unroll
    for (int st = 0; st < 2; ++st)
        #pragma unroll
        for (int e = 0; e < 8; ++e) {
            float p = __expf(sf[st * 2 + (e >> 2)][e & 3] - m);
            lsum += p;
            pa[st][e] = (bf16_t)p;
        }

    // PV: V pre-permuted in LDS -> fragment is a single contiguous bf16x8
    #pragma unroll
    for (int st = 0; st < 2; ++st)
        #pragma unroll
        for (int df = 0; df < 4; ++df) {
            bf16x8 vf = *reinterpret_cast<const bf16x8*>(&Vs[df * 16 + q15][st * 32 + g * 8]);
            O[df] = mfma16(pa[st], vf, O[df]);
        }
}

// ---------------- differential attention + per-head LN ----------------
__global__ __launch_bounds__(256)
void attn_kernel(const bf16_t* __restrict__ Qr, const bf16_t* __restrict__ Kr,
                 const bf16_t* __restrict__ Vt, const float* __restrict__ lambda_param,
                 bf16_t* __restrict__ ctx)
{
    __shared__ __align__(16) bf16_t K1s[64][72];
    __shared__ __align__(16) bf16_t K2s[64][72];
    __shared__ __align__(16) bf16_t Vs[64][72];   // [d][slot u] (pre-permuted keys)

    const int bh = blockIdx.y, b = bh / HH, h = bh % HH;
    const int s0 = blockIdx.x * 64;
    const int tid = threadIdx.x, w = tid >> 6, lane = tid & 63, q15 = lane & 15, g = lane >> 4;
    const float lam = 1.0f / (1.0f + __expf(-lambda_param[0]));

    const bf16_t* Q1p = Qr + (((size_t)(b * 2 + 0) * HH + h) * SS + (s0 + w * 16 + q15)) * DD;
    const bf16_t* Q2p = Qr + (((size_t)(b * 2 + 1) * HH + h) * SS + (s0 + w * 16 + q15)) * DD;
    bf16x8 qf1[2], qf2[2];
    qf1[0] = *reinterpret_cast<const bf16x8*>(Q1p + g * 8);
    qf1[1] = *reinterpret_cast<const bf16x8*>(Q1p + 32 + g * 8);
    qf2[0] = *reinterpret_cast<const bf16x8*>(Q2p + g * 8);
    qf2[1] = *reinterpret_cast<const bf16x8*>(Q2p + 32 + g * 8);

    const bf16_t* K1base = Kr + ((size_t)(b * 2 + 0) * HH + h) * SS * DD;
    const bf16_t* K2base = Kr + ((size_t)(b * 2 + 1) * HH + h) * SS * DD;
    const bf16_t* Vbase  = Vt + ((size_t)b * HH + h) * DD * SS;   // row d, stride SS

    float m1 = 0.f, l1 = 0.f, m2 = 0.f, l2 = 0.f;   // defer-max: init m=0, P <= e^8
    f32x4 O1[4], O2[4];
    #pragma unroll
    for (int df = 0; df < 4; ++df) {
        O1[df] = f32x4{0.f, 0.f, 0.f, 0.f};
        O2[df] = f32x4{0.f, 0.f, 0.f, 0.f};
    }

    const int srow = tid >> 3, scol = (tid & 7) * 8;
    // V permuted-store column base: keys scol..scol+7 -> slots u0..u0+3, u0+8..u0+11
    const int u0 = (scol & 32) + ((scol & 15) >> 2) * 8 + ((scol >> 4) & 1) * 4;

    bf16x8 rK1[2], rK2[2], rV[2];   // T14 register prefetch
    #pragma unroll
    for (int ii = 0; ii < 2; ++ii) {
        int r2 = srow + ii * 32;
        rK1[ii] = *reinterpret_cast<const bf16x8*>(&K1base[(size_t)r2 * DD + scol]);
        rK2[ii] = *reinterpret_cast<const bf16x8*>(&K2base[(size_t)r2 * DD + scol]);
        rV[ii]  = *reinterpret_cast<const bf16x8*>(&Vbase[(size_t)r2 * SS + scol]);
    }

    for (int kb = 0; kb < SS; kb += 64) {
        if (kb) __syncthreads();    // prev tile's reads done before overwrite
        #pragma unroll
        for (int ii = 0; ii < 2; ++ii) {
            int r2 = srow + ii * 32;
            *reinterpret_cast<bf16x8*>(&K1s[r2][scol]) = rK1[ii];
            *reinterpret_cast<bf16x8*>(&K2s[r2][scol]) = rK2[ii];
            bf16x4 lo = __builtin_shufflevector(rV[ii], rV[ii], 0, 1, 2, 3);
            bf16x4 hi = __builtin_shufflevector(rV[ii], rV[ii], 4, 5, 6, 7);
            *reinterpret_cast<bf16x4*>(&Vs[r2][u0])     = lo;
            *reinterpret_cast<bf16x4*>(&Vs[r2][u0 + 8]) = hi;
        }
        __syncthreads();
        if (kb + 64 < SS) {     // issue next tile's loads; latency hides under compute
            int kn = kb + 64;
            #pragma unroll
            for (int ii = 0; ii < 2; ++ii) {
                int r2 = srow + ii * 32;
                rK1[ii] = *reinterpret_cast<const bf16x8*>(&K1base[(size_t)(kn + r2) * DD + scol]);
                rK2[ii] = *reinterpret_cast<const bf16x8*>(&K2base[(size_t)(kn + r2) * DD + scol]);
                rV[ii]  = *reinterpret_cast<const bf16x8*>(&Vbase[(size_t)r2 * SS + kn + scol]);
            }
        }
        attn_branch(K1s, qf1, Vs, q15, g, m1, l1, O1);
        attn_branch(K2s, qf2, Vs, q15, g, m2, l2, O2);
    }

    // reduce lane-local l partials across the 4 g-lanes of each q-row
    l1 += __shfl_xor(l1, 16); l1 += __shfl_xor(l1, 32);
    l2 += __shfl_xor(l2, 16); l2 += __shfl_xor(l2, 32);

    float rl1[4], rl2[4];
    #pragma unroll
    for (int r = 0; r < 4; ++r) {
        rl1[r] = __shfl(l1, g * 4 + r);
        rl2[r] = __shfl(l2, g * 4 + r);
    }
    float cv[4][4];   // [df][r]
    #pragma unroll
    for (int df = 0; df < 4; ++df)
        #pragma unroll
        for (int r = 0; r < 4; ++r)
            cv[df][r] = O1[df][r] / rl1[r] - lam * (O2[df][r] / rl2[r]);

    #pragma unroll
    for (int r = 0; r < 4; ++r) {
        float sum = cv[0][r] + cv[1][r] + cv[2][r] + cv[3][r];
        sum += __shfl_xor(sum, 1); sum += __shfl_xor(sum, 2);
        sum += __shfl_xor(sum, 4); sum += __shfl_xor(sum, 8);
        float mu = sum * (1.0f / 64.0f);
        float vac = 0.f;
        #pragma unroll
        for (int df = 0; df < 4; ++df) { float dv = cv[df][r] - mu; vac += dv * dv; }
        vac += __shfl_xor(vac, 1); vac += __shfl_xor(vac, 2);
        vac += __shfl_xor(vac, 4); vac += __shfl_xor(vac, 8);
        float rs = rsqrtf(vac * (1.0f / 64.0f) + 1e-5f);
        int s = s0 + w * 16 + g * 4 + r;
        size_t rowoff = ((size_t)b * SS + s) * EE + h * DD;
        #pragma unroll
        for (int df = 0; df < 4; ++df)
            ctx[rowoff + df * 16 + q15] = (bf16_t)((cv[df][r] - mu) * rs * 0.5f);
    }
}

// ---------------- output projection: out = (ctx @ Wo + bo) * o_scale (f32) ----------------
__global__ __launch_bounds__(256)
void gemm_out_kernel(const bf16_t* __restrict__ ctxb, const bf16_t* __restrict__ WoT,
                     const float* __restrict__ bo, const float* __restrict__ os,
                     float* __restrict__ out)
{
    __shared__ __align__(16) bf16_t As[128][72];
    __shared__ __align__(16) bf16_t Bs[128][72];
    const int tid = threadIdx.x;
    const int w = tid >> 6, lane = tid & 63, q15 = lane & 15, g = lane >> 4;
    const int m0 = blockIdx.x * 128;
    const int nloc0 = blockIdx.y * 128;

    f32x4 acc[4][4];
    #pragma unroll
    for (int i = 0; i < 4; ++i)
        #pragma unroll
        for (int j = 0; j < 4; ++j)
            acc[i][j] = f32x4{0.f, 0.f, 0.f, 0.f};

    const int srow = tid >> 3, scol = (tid & 7) * 8;
    for (int k0 = 0; k0 < 768; k0 += 64) {
        #pragma unroll
        for (int rr = srow; rr < 128; rr += 32) {
            *reinterpret_cast<bf16x8*>(&As[rr][scol]) =
                *reinterpret_cast<const bf16x8*>(&ctxb[(size_t)(m0 + rr) * 768 + k0 + scol]);
            *reinterpret_cast<bf16x8*>(&Bs[rr][scol]) =
                *reinterpret_cast<const bf16x8*>(&WoT[(size_t)(nloc0 + rr) * 768 + k0 + scol]);
        }
        __syncthreads();
        const int ar0 = (w >> 1) * 64, bc0 = (w & 1) * 64;
        #pragma unroll
        for (int st = 0; st < 2; ++st) {
            bf16x8 af[4], bfr[4];
            #pragma unroll
            for (int i = 0; i < 4; ++i)
                af[i] = *reinterpret_cast<const bf16x8*>(&As[ar0 + i * 16 + q15][st * 32 + g * 8]);
            #pragma unroll
            for (int j = 0; j < 4; ++j)
                bfr[j] = *reinterpret_cast<const bf16x8*>(&Bs[bc0 + j * 16 + q15][st * 32 + g * 8]);
            #pragma unroll
            for (int i = 0; i < 4; ++i)
                #pragma unroll
                for (int j = 0; j < 4; ++j)
                    acc[i][j] = mfma16(af[i], bfr[j], acc[i][j]);
        }
        __syncthreads();
    }

    const int mbase = m0 + (w >> 1) * 64;
    const int nbase = nloc0 + (w & 1) * 64;
    #pragma unroll
    for (int j = 0; j < 4; ++j) {
        const int n = nbase + j * 16 + q15;
        const float bi = bo[n], sc = os[n];
        #pragma unroll
        for (int i = 0; i < 4; ++i)
            #pragma unroll
            for (int r = 0; r < 4; ++r) {
                int m = mbase + i * 16 + g * 4 + r;
                out[(size_t)m * 768 + n] = (acc[i][j][r] + bi) * sc;
            }
    }
}

// ---------------- launch ----------------
extern "C" void kernel_launch(void* const* d_in, const int* in_sizes, int n_in,
                              void* d_out, int out_size, void* d_ws, size_t ws_size,
                              hipStream_t stream)
{
    (void)in_sizes; (void)n_in; (void)out_size; (void)ws_size;
    const float* x  = (const float*)d_in[0];
    const float* Wq = (const float*)d_in[1];
    const float* bq = (const float*)d_in[2];
    const float* Wk = (const float*)d_in[3];
    const float* bk = (const float*)d_in[4];
    const float* Wv = (const float*)d_in[5];
    const float* bv = (const float*)d_in[6];
    const float* Wo = (const float*)d_in[7];
    const float* bo = (const float*)d_in[8];
    const float* qs = (const float*)d_in[9];
    const float* ks = (const float*)d_in[10];
    const float* vs = (const float*)d_in[11];
    const float* os = (const float*)d_in[12];
    const float* lp = (const float*)d_in[13];
    float* out = (float*)d_out;

    char* ws = (char*)d_ws;
    bf16_t* xb   = (bf16_t*)(ws);                  // 4096*768*2      = 6291456
    bf16_t* WqT  = (bf16_t*)(ws + 6291456);        // 1536*768*2      = 2359296
    bf16_t* WkT  = (bf16_t*)(ws + 8650752);        // 2359296
    bf16_t* WvT  = (bf16_t*)(ws + 11010048);       // 768*768*2       = 1179648
    bf16_t* WoT  = (bf16_t*)(ws + 12189696);       // 1179648
    bf16_t* Qr   = (bf16_t*)(ws + 13369344);       // 2*2*12*2048*64*2 = 12582912
    bf16_t* Kr   = (bf16_t*)(ws + 25952256);       // 12582912
    bf16_t* Vt   = (bf16_t*)(ws + 38535168);       // 2*12*64*2048*2  = 6291456
    bf16_t* ctxb = (bf16_t*)(ws + 44826624);       // 4096*768*2      = 6291456
    float*  ctab = (float*)(ws + 51118080);        // 2048*32*4       = 262144
    float*  stab = (float*)(ws + 51380224);        // 262144  -> total 51642368

    cast_x_kernel<<<dim3(1536), dim3(256), 0, stream>>>(x, xb, MM * EE);
    transpose_cast_kernel<<<dim3(48, 24), dim3(256), 0, stream>>>(Wq, WqT, 768, 1536);
    transpose_cast_kernel<<<dim3(48, 24), dim3(256), 0, stream>>>(Wk, WkT, 768, 1536);
    transpose_cast_kernel<<<dim3(24, 24), dim3(256), 0, stream>>>(Wv, WvT, 768, 768);
    transpose_cast_kernel<<<dim3(24, 24), dim3(256), 0, stream>>>(Wo, WoT, 768, 768);
    rope_table_kernel<<<dim3(256), dim3(256), 0, stream>>>(ctab, stab);
    gemm_qkv_kernel<<<dim3(32, 30), dim3(256), 0, stream>>>(xb, WqT, WkT, WvT,
                                                            bq, bk, bv, qs, ks, vs,
                                                            ctab, stab, Qr, Kr, Vt);
    attn_kernel<<<dim3(32, 24), dim3(256), 0, stream>>>(Qr, Kr, Vt, lp, ctxb);
    gemm_out_kernel<<<dim3(32, 6), dim3(256), 0, stream>>>(ctxb, WoT, bo, os, out);
}